// Round 9
// baseline (357.784 us; speedup 1.0000x reference)
//
#include <hip/hip_runtime.h>
#include <math.h>

#define NB 32        // batches
#define NP 512       // N == M == 512
#define ITERS 50
#define EPSV   0.05f
#define INVEPS 20.0f

// ---- R8 paired-gang geometry: 16 pairs x 16 blocks, 32 rows/batch/block ----
#define NPAIR 16
#define GG 16                          // blocks per pair-gang
#define RPB2 32                        // rows per block per batch
#define PAR_STRIDE2 (NPAIR*2*GG*NP)    // 262144 u32 per parity buffer
#define N_PACK2 (2*PAR_STRIDE2)        // 2 MiB
// ---- legacy R7 geometry (fallback when ws < 2 MiB) ----
#define RG 8
#define RPB 64
#define N_PACK (2*NB*RG*NP)            // 1 MiB

typedef unsigned long long u64;
typedef unsigned int u32;

// ---- relaxed agent-scope (device-coherent, IC) primitives ----
// R6 proved this is the ONLY working CU-to-CU transport on gfx950.
__device__ __forceinline__ void st32(u32* p, u32 v) {
  __hip_atomic_store(p, v, __ATOMIC_RELAXED, __HIP_MEMORY_SCOPE_AGENT);
}
__device__ __forceinline__ u32 ld32(const u32* p) {
  return __hip_atomic_load(p, __ATOMIC_RELAXED, __HIP_MEMORY_SCOPE_AGENT);
}
__device__ __forceinline__ void st64f(float2* p, float tag, float val) {
  union { float2 f; u64 u; } c; c.f = make_float2(tag, val);
  __hip_atomic_store((u64*)p, c.u, __ATOMIC_RELAXED, __HIP_MEMORY_SCOPE_AGENT);
}
__device__ __forceinline__ float2 ld64f(const float2* p) {
  union { u64 u; float2 f; } c;
  c.u = __hip_atomic_load((const u64*)p, __ATOMIC_RELAXED, __HIP_MEMORY_SCOPE_AGENT);
  return c.f;
}

// tag for iteration k: nibble LUT over k%6 -> {1,3,4,5,6,7}; poison low3=2
// never matches; all tags in any 6-window distinct (stale detect exact).
__device__ __forceinline__ u32 tag_of(int k) {
  return (0x765431u >> (4 * (k % 6))) & 0xFu;
}
__device__ __forceinline__ u32 pack_slot(float v, u32 tag) {
  return (__float_as_uint(v) & ~7u) | tag;
}

// =====================================================================
// R9 = R8 resubmit (R8's error matched R2's infra-failure signature; audit
// found no deadlock mechanism) with fail-fast hardening: main-loop gather
// bails cut 1<<24 -> 1<<16 sweeps (broken gang => wrong answer, visible
// test failure in ~ms, never a wedged container) + s_sleep backoff after
// 64 sweeps. Design unchanged:
//
// Paired-batch interleaved gang. One 512-thread block serves 32 rows of
// BOTH batches of a pair; batch X's publish->IC-visibility latency is
// filled by batch Y's B+C compute (phase-locked in-block interleave).
// Rendezvous protocol = R7 verbatim (agent/IC, tags, post-publish spec
// issue, pend-loop), 15 remote streams per batch.
// =====================================================================
__global__ __launch_bounds__(NP, 2) void emd_pair_kernel(
    const float* __restrict__ a_mask, const float* __restrict__ pc_a,
    const float* __restrict__ b_mask, const float* __restrict__ pc_b,
    u32* __restrict__ pack, float2* __restrict__ epi,
    float* __restrict__ out)
{
  const int rb = blockIdx.x;
  const int p  = rb >> 4;            // pair 0..15
  const int g  = rb & 15;            // gang position 0..15
  const int X  = 2*p, Y = 2*p + 1;   // the two batches
  const int t  = threadIdx.x;
  const int chunk = t & 15;          // 16 threads per row
  const int lrow  = t >> 4;          // local row 0..31
  const int grow  = g*RPB2 + lrow;   // global row (same split for X and Y)
  const int lane  = t & 63, wid = t >> 6;

  __shared__ __align__(16) float rhoX_l[NP], rhoY_l[NP];
  __shared__ __align__(16) float bwX_l[NP],  bwY_l[NP];
  __shared__ __align__(16) float uX_l[RPB2], uY_l[RPB2];
  __shared__ __align__(16) float sm[NP];
  __shared__ float red[32];

  float4 eKregX[8], eKregY[8];       // row slice: row grow, cols 64cc+4chunk+e
  float  eKcolX[RPB2], eKcolY[RPB2]; // col slice: col t, rows g*32+i
  float  aw_rX, bw_tX, hubX;
  float  aw_rY, bw_tY, hubY;

  // pack layout: [par][ (batch)*GG + g ][NP]
  u32* ownX = pack + ((size_t)(X*GG + g))*NP + t;
  u32* ownY = pack + ((size_t)(Y*GG + g))*NP + t;
  const u32* baseX = pack + (size_t)X*GG*NP + t;
  const u32* baseY = pack + (size_t)Y*GG*NP + t;

  // ================= setup =================
  const float aptX = a_mask[X*NP+t] * pc_a[((size_t)X*NP+t)*3+2];
  const float bptX = b_mask[X*NP+t] * pc_b[((size_t)X*NP+t)*3+2];
  const float aptY = a_mask[Y*NP+t] * pc_a[((size_t)Y*NP+t)*3+2];
  const float bptY = b_mask[Y*NP+t] * pc_b[((size_t)Y*NP+t)*3+2];
  {
    float r0 = aptX, r1 = bptX, r2 = aptY, r3 = bptY;
    #pragma unroll
    for (int o = 32; o; o >>= 1) {
      r0 += __shfl_xor(r0, o); r1 += __shfl_xor(r1, o);
      r2 += __shfl_xor(r2, o); r3 += __shfl_xor(r3, o);
    }
    if (lane == 0) { red[wid]=r0; red[8+wid]=r1; red[16+wid]=r2; red[24+wid]=r3; }
    __syncthreads();
    float asX=0.f, bsX=0.f, asY=0.f, bsY=0.f;
    #pragma unroll
    for (int w = 0; w < 8; ++w) {
      asX += red[w]; bsX += red[8+w]; asY += red[16+w]; bsY += red[24+w];
    }
    const float eX = asX - bsX, aeX = fabsf(eX);
    hubX = (aeX <= 1.f) ? 0.5f*eX*eX : (aeX - 0.5f);
    const float eY = asY - bsY, aeY = fabsf(eY);
    hubY = (aeY <= 1.f) ? 0.5f*eY*eY : (aeY - 0.5f);
    sm[t]    = (aptX > 0.f) ? aptX/asX : 0.f;   // awX
    bwX_l[t] = (bptX > 0.f) ? bptX/bsX : 0.f;
    bwY_l[t] = (bptY > 0.f) ? bptY/bsY : 0.f;
    __syncthreads();
    aw_rX = sm[grow]; bw_tX = bwX_l[t]; bw_tY = bwY_l[t];
    // ---- batch X K caches
    {
      const float ax = pc_a[((size_t)X*NP+grow)*3+0];
      const float ay = pc_a[((size_t)X*NP+grow)*3+1];
      const bool  va = aw_rX > 0.f;
      #pragma unroll
      for (int cc = 0; cc < 8; ++cc) {
        float r[4];
        #pragma unroll
        for (int e2 = 0; e2 < 4; ++e2) {
          const int col = 64*cc + 4*chunk + e2;
          const float bx = pc_b[((size_t)X*NP+col)*3+0];
          const float by = pc_b[((size_t)X*NP+col)*3+1];
          const bool  vb = bwX_l[col] > 0.f;
          const float dx = ax-bx, dy = ay-by;
          const float d  = sqrtf(dx*dx + dy*dy + 1e-12f);
          r[e2] = (va && vb) ? __expf((-INVEPS)*d) : 1.f;
        }
        eKregX[cc] = make_float4(r[0], r[1], r[2], r[3]);
      }
      const float bx0 = pc_b[((size_t)X*NP+t)*3+0];
      const float by0 = pc_b[((size_t)X*NP+t)*3+1];
      const bool  vb0 = bw_tX > 0.f;
      #pragma unroll
      for (int i = 0; i < RPB2; ++i) {
        const int row = g*RPB2 + i;
        const float axi = pc_a[((size_t)X*NP+row)*3+0];  // wave-uniform
        const float ayi = pc_a[((size_t)X*NP+row)*3+1];
        const bool  vai = sm[row] > 0.f;
        const float dx = axi-bx0, dy = ayi-by0;
        const float d  = sqrtf(dx*dx + dy*dy + 1e-12f);
        eKcolX[i] = (vai && vb0) ? __expf((-INVEPS)*d) : 1.f;
      }
    }
    rhoX_l[t] = 1.f;
    __syncthreads();               // done reading sm = awX
    sm[t] = (aptY > 0.f) ? aptY/asY : 0.f;     // awY
    __syncthreads();
    aw_rY = sm[grow];
    // ---- batch Y K caches
    {
      const float ax = pc_a[((size_t)Y*NP+grow)*3+0];
      const float ay = pc_a[((size_t)Y*NP+grow)*3+1];
      const bool  va = aw_rY > 0.f;
      #pragma unroll
      for (int cc = 0; cc < 8; ++cc) {
        float r[4];
        #pragma unroll
        for (int e2 = 0; e2 < 4; ++e2) {
          const int col = 64*cc + 4*chunk + e2;
          const float bx = pc_b[((size_t)Y*NP+col)*3+0];
          const float by = pc_b[((size_t)Y*NP+col)*3+1];
          const bool  vb = bwY_l[col] > 0.f;
          const float dx = ax-bx, dy = ay-by;
          const float d  = sqrtf(dx*dx + dy*dy + 1e-12f);
          r[e2] = (va && vb) ? __expf((-INVEPS)*d) : 1.f;
        }
        eKregY[cc] = make_float4(r[0], r[1], r[2], r[3]);
      }
      const float bx0 = pc_b[((size_t)Y*NP+t)*3+0];
      const float by0 = pc_b[((size_t)Y*NP+t)*3+1];
      const bool  vb0 = bw_tY > 0.f;
      #pragma unroll
      for (int i = 0; i < RPB2; ++i) {
        const int row = g*RPB2 + i;
        const float axi = pc_a[((size_t)Y*NP+row)*3+0];
        const float ayi = pc_a[((size_t)Y*NP+row)*3+1];
        const bool  vai = sm[row] > 0.f;
        const float dx = axi-bx0, dy = ayi-by0;
        const float d  = sqrtf(dx*dx + dy*dy + 1e-12f);
        eKcolY[i] = (vai && vb0) ? __expf((-INVEPS)*d) : 1.f;
      }
    }
    rhoY_l[t] = 1.f;
    __syncthreads();
  }

  // ================= main loop =================
  for (int k = 1; k <= ITERS; ++k) {
    const u32 tag = tag_of(k);
    const size_t po = (size_t)(k & 1) * (size_t)PAR_STRIDE2;

    // ---- B_X: uX(k) = awX / sum_j ekX*rhoX(k-1)
    {
      const float4* r4p = (const float4*)rhoX_l;
      float dot = 0.f;
      #pragma unroll
      for (int cc = 0; cc < 8; ++cc) {
        const float4 g4 = r4p[16*cc + chunk];
        const float4 kk = eKregX[cc];
        dot += kk.x*g4.x + kk.y*g4.y + kk.z*g4.z + kk.w*g4.w;
      }
      #pragma unroll
      for (int o = 8; o; o >>= 1) dot += __shfl_xor(dot, o);  // 16-lane reduce
      if (chunk == 0) uX_l[lrow] = aw_rX / fmaxf(dot, 1e-38f);
    }
    __syncthreads();   // uX ready

    // ---- C_X: publish col partial for X; spec-issue gang X (post-publish)
    float scoX;
    {
      const float4* u4p = (const float4*)uX_l;
      float sc = 0.f;
      #pragma unroll
      for (int i4 = 0; i4 < 8; ++i4) {
        const float4 uu = u4p[i4];
        sc += eKcolX[4*i4+0]*uu.x + eKcolX[4*i4+1]*uu.y
            + eKcolX[4*i4+2]*uu.z + eKcolX[4*i4+3]*uu.w;
      }
      scoX = sc;
      st32(ownX + po, pack_slot(sc, tag));
    }
    u32 qx[GG];
    #pragma unroll
    for (int r = 0; r < GG; ++r)
      if (r != g) qx[r] = ld32(baseX + po + (size_t)r*NP);
    asm volatile("" ::: "memory");   // pin spec-X issue before B_Y

    // ---- B_Y (fills X's visibility window)
    {
      const float4* r4p = (const float4*)rhoY_l;
      float dot = 0.f;
      #pragma unroll
      for (int cc = 0; cc < 8; ++cc) {
        const float4 g4 = r4p[16*cc + chunk];
        const float4 kk = eKregY[cc];
        dot += kk.x*g4.x + kk.y*g4.y + kk.z*g4.z + kk.w*g4.w;
      }
      #pragma unroll
      for (int o = 8; o; o >>= 1) dot += __shfl_xor(dot, o);
      if (chunk == 0) uY_l[lrow] = aw_rY / fmaxf(dot, 1e-38f);
    }
    __syncthreads();   // uY ready

    // ---- C_Y: publish Y; spec-issue gang Y
    float scoY;
    {
      const float4* u4p = (const float4*)uY_l;
      float sc = 0.f;
      #pragma unroll
      for (int i4 = 0; i4 < 8; ++i4) {
        const float4 uu = u4p[i4];
        sc += eKcolY[4*i4+0]*uu.x + eKcolY[4*i4+1]*uu.y
            + eKcolY[4*i4+2]*uu.z + eKcolY[4*i4+3]*uu.w;
      }
      scoY = sc;
      st32(ownY + po, pack_slot(sc, tag));
    }
    u32 qy[GG];
    #pragma unroll
    for (int r = 0; r < GG; ++r)
      if (r != g) qy[r] = ld32(baseY + po + (size_t)r*NP);
    asm volatile("" ::: "memory");

    // ---- gather X (publish_X was ~B_Y+C_Y ago: mostly visible already)
    {
      unsigned pend = 0xFFFFu & ~(1u << g);
      int sweeps = 0;
      while (true) {
        unsigned np = 0;
        #pragma unroll
        for (int r = 0; r < GG; ++r)
          if ((pend >> r) & 1u)
            if ((qx[r] & 7u) != tag) np |= (1u << r);
        pend = np;
        if (!pend) break;
        #pragma unroll
        for (int r = 0; r < GG; ++r)
          if ((pend >> r) & 1u)
            qx[r] = ld32(baseX + po + (size_t)r*NP);
        ++sweeps;
        if (sweeps > 64) __builtin_amdgcn_s_sleep(1);   // pathological only
        if (sweeps > (1<<16)) break;   // fail FAST and visibly, never wedge
      }
      float S = scoX;
      #pragma unroll
      for (int r = 0; r < GG; ++r)
        if (r != g) S += __uint_as_float(qx[r]);   // <=7 ulp tag noise
      rhoX_l[t] = bw_tX / fmaxf(S, 1e-38f);
    }

    // ---- gather Y
    {
      unsigned pend = 0xFFFFu & ~(1u << g);
      int sweeps = 0;
      while (true) {
        unsigned np = 0;
        #pragma unroll
        for (int r = 0; r < GG; ++r)
          if ((pend >> r) & 1u)
            if ((qy[r] & 7u) != tag) np |= (1u << r);
        pend = np;
        if (!pend) break;
        #pragma unroll
        for (int r = 0; r < GG; ++r)
          if ((pend >> r) & 1u)
            qy[r] = ld32(baseY + po + (size_t)r*NP);
        ++sweeps;
        if (sweeps > 64) __builtin_amdgcn_s_sleep(1);
        if (sweeps > (1<<16)) break;
      }
      float S = scoY;
      #pragma unroll
      for (int r = 0; r < GG; ++r)
        if (r != g) S += __uint_as_float(qy[r]);
      rhoY_l[t] = bw_tY / fmaxf(S, 1e-38f);
    }
    __syncthreads();   // rhoX, rhoY ready for next iteration
  }

  // ================= epilogue: ot partials for X and Y =================
  float accX = 0.f, accY = 0.f;
  {
    const float urX = uX_l[lrow];
    const float4* r4p = (const float4*)rhoX_l;
    #pragma unroll
    for (int cc = 0; cc < 8; ++cc) {
      const float4 g4 = r4p[16*cc + chunk];
      const float4 kk = eKregX[cc];
      const float ek[4] = {kk.x, kk.y, kk.z, kk.w};
      const float vv[4] = {g4.x, g4.y, g4.z, g4.w};
      #pragma unroll
      for (int e2 = 0; e2 < 4; ++e2) {
        const float lk = __logf(fmaxf(ek[e2], 1e-38f));
        const float d2 = (EPSV*lk)*(EPSV*lk);
        const float v  = d2 * urX * ek[e2] * vv[e2];
        accX += (ek[e2] > 0.f) ? v : 0.f;
      }
    }
  }
  {
    const float urY = uY_l[lrow];
    const float4* r4p = (const float4*)rhoY_l;
    #pragma unroll
    for (int cc = 0; cc < 8; ++cc) {
      const float4 g4 = r4p[16*cc + chunk];
      const float4 kk = eKregY[cc];
      const float ek[4] = {kk.x, kk.y, kk.z, kk.w};
      const float vv[4] = {g4.x, g4.y, g4.z, g4.w};
      #pragma unroll
      for (int e2 = 0; e2 < 4; ++e2) {
        const float lk = __logf(fmaxf(ek[e2], 1e-38f));
        const float d2 = (EPSV*lk)*(EPSV*lk);
        const float v  = d2 * urY * ek[e2] * vv[e2];
        accY += (ek[e2] > 0.f) ? v : 0.f;
      }
    }
  }
  sm[t] = accX; bwX_l[t] = accY;   // bwX_l free post-loop (bw_tX is in reg)
  __syncthreads();
  if (t < 64) {
    float vX = 0.f, vY = 0.f;
    #pragma unroll
    for (int q2 = 0; q2 < 8; ++q2) { vX += sm[t*8+q2]; vY += bwX_l[t*8+q2]; }
    #pragma unroll
    for (int o = 32; o; o >>= 1) { vX += __shfl_xor(vX, o); vY += __shfl_xor(vY, o); }
    if (t == 0) {
      st64f(epi + (size_t)X*GG + g, 51.f, vX);
      st64f(epi + (size_t)Y*GG + g, 51.f, vY);
    }
  }
  if (g == 0 && t < 2*GG) {   // lanes 0-15: X, lanes 16-31: Y (concurrent)
    const int bxl = t >> 4;
    const int gg  = t & 15;
    const float2* ep = epi + (size_t)(X + bxl)*GG + gg;
    float2 pr;
    long long spins = 0;
    do {
      pr = ld64f(ep);
      if (pr.x == 51.f) break;
      __builtin_amdgcn_s_sleep(1);
    } while (++spins < (1LL<<24));
    float v = pr.y;
    #pragma unroll
    for (int o = 8; o; o >>= 1) v += __shfl_xor(v, o);  // 16-group reduce
    if (gg == 0) out[X + bxl] = v + (bxl ? hubY : hubX);
  }
}

// =====================================================================
// R7 fallback (verbatim champion, 147us) — used when ws < 2 MiB + epi.
// =====================================================================
__global__ __launch_bounds__(NP) void emd_kernel_r7(
    const float* __restrict__ a_mask, const float* __restrict__ pc_a,
    const float* __restrict__ b_mask, const float* __restrict__ pc_b,
    u32* __restrict__ pack, float2* __restrict__ epi,
    float* __restrict__ out)
{
  const int rb = blockIdx.x;
  const int b  = rb >> 3;
  const int rg = rb & 7;
  const int t  = threadIdx.x;
  const int chunk = t & 7;
  const int lrow  = t >> 3;
  const int grow  = rg*RPB + lrow;
  const int lane  = t & 63, wid = t >> 6;

  __shared__ __align__(16) float rho_l[NP];
  __shared__ __align__(16) float bw_l[NP];
  __shared__ __align__(16) float u_l[RPB];
  __shared__ __align__(16) float sm[NP];
  __shared__ float red[16];

  float4 eKreg[16];
  float  eKcol[RPB];
  float  aw_r, bw_t, hub = 0.f;

  {
    const float apt = a_mask[b*NP+t] * pc_a[((size_t)b*NP+t)*3+2];
    const float bpt = b_mask[b*NP+t] * pc_b[((size_t)b*NP+t)*3+2];
    float ra = apt, rv = bpt;
    #pragma unroll
    for (int o = 32; o; o >>= 1) { ra += __shfl_xor(ra, o); rv += __shfl_xor(rv, o); }
    if (lane == 0) { red[wid] = ra; red[8+wid] = rv; }
    __syncthreads();
    float asum = 0.f, bsum = 0.f;
    #pragma unroll
    for (int w = 0; w < 8; ++w) { asum += red[w]; bsum += red[8+w]; }
    const float e = asum - bsum, ae = fabsf(e);
    hub = (ae <= 1.f) ? 0.5f*e*e : (ae - 0.5f);
    sm[t]   = (apt > 0.f) ? apt/asum : 0.f;
    bw_l[t] = (bpt > 0.f) ? bpt/bsum : 0.f;
    __syncthreads();
    aw_r = sm[grow];
    bw_t = bw_l[t];
    const float ax = pc_a[((size_t)b*NP+grow)*3+0];
    const float ay = pc_a[((size_t)b*NP+grow)*3+1];
    const bool  va = aw_r > 0.f;
    #pragma unroll
    for (int cc = 0; cc < 16; ++cc) {
      float r[4];
      #pragma unroll
      for (int e2 = 0; e2 < 4; ++e2) {
        const int col = 32*cc + 4*chunk + e2;
        const float bx = pc_b[((size_t)b*NP+col)*3+0];
        const float by = pc_b[((size_t)b*NP+col)*3+1];
        const bool  vb = bw_l[col] > 0.f;
        const float dx = ax-bx, dy = ay-by;
        const float d  = sqrtf(dx*dx + dy*dy + 1e-12f);
        r[e2] = (va && vb) ? __expf((-INVEPS)*d) : 1.f;
      }
      eKreg[cc] = make_float4(r[0], r[1], r[2], r[3]);
    }
    const float bx0 = pc_b[((size_t)b*NP+t)*3+0];
    const float by0 = pc_b[((size_t)b*NP+t)*3+1];
    const bool  vb0 = bw_t > 0.f;
    #pragma unroll
    for (int i = 0; i < RPB; ++i) {
      const int row = rg*RPB + i;
      const float axi = pc_a[((size_t)b*NP+row)*3+0];
      const float ayi = pc_a[((size_t)b*NP+row)*3+1];
      const bool  vai = sm[row] > 0.f;
      const float dx = axi-bx0, dy = ayi-by0;
      const float d  = sqrtf(dx*dx + dy*dy + 1e-12f);
      eKcol[i] = (vai && vb0) ? __expf((-INVEPS)*d) : 1.f;
    }
    rho_l[t] = 1.f;
    __syncthreads();
  }

  for (int k = 1; k <= ITERS; ++k) {
    const u32 tag = tag_of(k);
    const int par = k & 1;
    const u32* base = pack + ((size_t)par*NB + b)*RG*NP + t;
    {
      const float4* r4p = (const float4*)rho_l;
      float dot = 0.f;
      #pragma unroll
      for (int cc = 0; cc < 16; ++cc) {
        const float4 g4 = r4p[8*cc + chunk];
        const float4 kk = eKreg[cc];
        dot += kk.x*g4.x + kk.y*g4.y + kk.z*g4.z + kk.w*g4.w;
      }
      #pragma unroll
      for (int o = 4; o; o >>= 1) dot += __shfl_xor(dot, o);
      if (chunk == 0) u_l[lrow] = aw_r / fmaxf(dot, 1e-38f);
    }
    __syncthreads();
    float sc_own;
    {
      const float4* u4p = (const float4*)u_l;
      float sc = 0.f;
      #pragma unroll
      for (int i4 = 0; i4 < 16; ++i4) {
        const float4 uu = u4p[i4];
        sc += eKcol[4*i4+0]*uu.x + eKcol[4*i4+1]*uu.y
            + eKcol[4*i4+2]*uu.z + eKcol[4*i4+3]*uu.w;
      }
      sc_own = sc;
      st32(pack + (((size_t)par*NB + b)*RG + rg)*NP + t, pack_slot(sc, tag));
    }
    u32 q[RG];
    #pragma unroll
    for (int r = 0; r < RG; ++r)
      if (r != rg) q[r] = ld32(base + (size_t)r*NP);
    {
      unsigned pend = 0xFFu & ~(1u << rg);
      long long sweeps = 0;
      while (true) {
        unsigned np = 0;
        #pragma unroll
        for (int r = 0; r < RG; ++r)
          if ((pend >> r) & 1u)
            if ((q[r] & 7u) != tag) np |= (1u << r);
        pend = np;
        if (!pend) break;
        #pragma unroll
        for (int r = 0; r < RG; ++r)
          if ((pend >> r) & 1u)
            q[r] = ld32(base + (size_t)r*NP);
        if (++sweeps > (1LL<<22)) break;
      }
      float S = sc_own;
      #pragma unroll
      for (int r = 0; r < RG; ++r)
        if (r != rg) S += __uint_as_float(q[r]);
      rho_l[t] = bw_t / fmaxf(S, 1e-38f);
    }
    __syncthreads();
  }

  float acc = 0.f;
  {
    const float ur = u_l[lrow];
    const float4* r4p = (const float4*)rho_l;
    #pragma unroll
    for (int cc = 0; cc < 16; ++cc) {
      const float4 g4 = r4p[8*cc + chunk];
      const float4 kk = eKreg[cc];
      const float ek[4] = {kk.x, kk.y, kk.z, kk.w};
      const float vv[4] = {g4.x, g4.y, g4.z, g4.w};
      #pragma unroll
      for (int e2 = 0; e2 < 4; ++e2) {
        const float lk = __logf(fmaxf(ek[e2], 1e-38f));
        const float d2 = (EPSV*lk)*(EPSV*lk);
        const float v  = d2 * ur * ek[e2] * vv[e2];
        acc += (ek[e2] > 0.f) ? v : 0.f;
      }
    }
  }
  sm[t] = acc;
  __syncthreads();
  if (t < 64) {
    float v = 0.f;
    #pragma unroll
    for (int q2 = 0; q2 < 8; ++q2) v += sm[t*8+q2];
    #pragma unroll
    for (int o = 32; o; o >>= 1) v += __shfl_xor(v, o);
    if (t == 0) st64f(epi + (size_t)b*RG + rg, 51.f, v);
  }
  if (rg == 0 && t < RG) {
    float2 pr;
    long long spins = 0;
    do {
      pr = ld64f(epi + (size_t)b*RG + t);
      if (pr.x == 51.f) break;
      __builtin_amdgcn_s_sleep(1);
    } while (++spins < (1LL<<24));
    float v = pr.y;
    #pragma unroll
    for (int o = 4; o; o >>= 1) v += __shfl_xor(v, o);
    if (t == 0) out[b] = v + hub;
  }
}

extern "C" void kernel_launch(void* const* d_in, const int* in_sizes, int n_in,
                              void* d_out, int out_size, void* d_ws, size_t ws_size,
                              hipStream_t stream) {
  const float* a_mask = (const float*)d_in[0];
  const float* pc_a   = (const float*)d_in[1];
  const float* b_mask = (const float*)d_in[2];
  const float* pc_b   = (const float*)d_in[3];
  float* out = (float*)d_out;
  u32* pack = (u32*)d_ws;
  (void)in_sizes; (void)n_in; (void)out_size;

  const size_t need_pair = (size_t)N_PACK2*4 + (size_t)NB*GG*sizeof(float2);
  if (ws_size >= need_pair) {
    float2* epi = (float2*)(pack + N_PACK2);
    emd_pair_kernel<<<NPAIR*GG, NP, 0, stream>>>(a_mask, pc_a, b_mask, pc_b,
                                                 pack, epi, out);
  } else {
    float2* epi = (float2*)(pack + N_PACK);
    emd_kernel_r7<<<NB*RG, NP, 0, stream>>>(a_mask, pc_a, b_mask, pc_b,
                                            pack, epi, out);
  }
}

// Round 10
// 202.831 us; speedup vs baseline: 1.7640x; 1.7640x over previous
//
#include <hip/hip_runtime.h>
#include <math.h>

#define NB 32        // batches
#define NP 512       // N == M == 512
#define RG 8         // row-groups (blocks) per batch
#define RPB 64       // rows per block
#define ITERS 50
#define EPSV   0.05f
#define INVEPS 20.0f

typedef unsigned long long u64;
typedef unsigned int u32;

// ws layout: pack[2][NB][RG][NP] u32 (row-major: each 512-col stream is a
// contiguous single-writer array -> no false sharing), then epi[NB][RG] float2.
// Poison safety: 0xAAAAAAAA low 3 bits = 2; tag set {1,3,4,5,6,7} never
// contains 2 and tag(k) != tag(k-2) (k mod 6 LUT). epi tag 51.0f != poison.
#define N_PACK (2*NB*RG*NP)

// ---- relaxed agent-scope (device-coherent, IC) primitives ----
// R6 proved agent/IC is the ONLY working CU-to-CU transport on gfx950.
// R10 probe: publish via atomic EXCHANGE — the RMW executes at the IC
// coherence point, so the value is remotely visible the moment it commits,
// bypassing plain-store write-path staging (the suspected ~5000cy of V).
__device__ __forceinline__ void st32_xchg(u32* p, u32 v) {
  (void)__hip_atomic_exchange(p, v, __ATOMIC_RELAXED, __HIP_MEMORY_SCOPE_AGENT);
}
__device__ __forceinline__ u32 ld32(const u32* p) {
  return __hip_atomic_load(p, __ATOMIC_RELAXED, __HIP_MEMORY_SCOPE_AGENT);
}
__device__ __forceinline__ void st64f(float2* p, float tag, float val) {
  union { float2 f; u64 u; } c; c.f = make_float2(tag, val);
  __hip_atomic_store((u64*)p, c.u, __ATOMIC_RELAXED, __HIP_MEMORY_SCOPE_AGENT);
}
__device__ __forceinline__ float2 ld64f(const float2* p) {
  union { u64 u; float2 f; } c;
  c.u = __hip_atomic_load((const u64*)p, __ATOMIC_RELAXED, __HIP_MEMORY_SCOPE_AGENT);
  return c.f;
}

// tag for iteration k: nibble LUT over k%6 -> {1,3,4,5,6,7} (proven r12/r14)
__device__ __forceinline__ u32 tag_of(int k) {
  return (0x765431u >> (4 * (k % 6))) & 0xFu;
}
// pack fp32 value with tag in low 3 mantissa bits (<=7 ulp perturbation)
__device__ __forceinline__ u32 pack_slot(float v, u32 tag) {
  return (__float_as_uint(v) & ~7u) | tag;
}

// ---------------- single fused kernel: setup + 50 linear-Sinkhorn iters + ot ----
// ONE batch per 512-thread block, 64 rows each, RG=8 blocks/batch, grid=256
// (1 block/CU, all resident -> spin rendezvous deadlock-free).
//
// R10 = R7 (champion, 147.3us) with ONE change: publish by atomic exchange.
// Falsification ledger: congestion (R3), sampling period (R5), medium (R1/
// R6), pre-publish spec staleness (R7 fixed, -6.4us), in-block chain pairing
// (R9). Residual: V = publish->visible+discovered ~5900cy, 6-7x one IC RT —
// points at store-path staging. Atomic swap commits AT the IC slice.
__global__ __launch_bounds__(NP) void emd_kernel(
    const float* __restrict__ a_mask, const float* __restrict__ pc_a,
    const float* __restrict__ b_mask, const float* __restrict__ pc_b,
    u32* __restrict__ pack, float2* __restrict__ epi,
    float* __restrict__ out)
{
  const int rb = blockIdx.x;
  const int b  = rb >> 3;            // batch (contiguous 8-block ranges)
  const int rg = rb & 7;             // row-group 0..7
  const int t  = threadIdx.x;
  const int chunk = t & 7;           // 8 threads per row
  const int lrow  = t >> 3;          // local row 0..63
  const int grow  = rg*RPB + lrow;
  const int lane  = t & 63, wid = t >> 6;

  __shared__ __align__(16) float rho_l[NP];   // exp(logv)
  __shared__ __align__(16) float bw_l[NP];    // col masses
  __shared__ __align__(16) float u_l[RPB];    // exp(logu)
  __shared__ __align__(16) float sm[NP];      // setup aw / epilogue scratch
  __shared__ float red[16];

  float4 eKreg[16];     // row slice: row=grow, cols 32*cc+4*chunk+e
  float  eKcol[RPB];    // col slice: col=t, rows rg*64+i
  float  aw_r, bw_t, hub = 0.f;

  // ================= setup: masses, huber, expK caches =================
  {
    const float apt = a_mask[b*NP+t] * pc_a[((size_t)b*NP+t)*3+2];
    const float bpt = b_mask[b*NP+t] * pc_b[((size_t)b*NP+t)*3+2];
    float ra = apt, rv = bpt;
    #pragma unroll
    for (int o = 32; o; o >>= 1) { ra += __shfl_xor(ra, o); rv += __shfl_xor(rv, o); }
    if (lane == 0) { red[wid] = ra; red[8+wid] = rv; }
    __syncthreads();
    float asum = 0.f, bsum = 0.f;
    #pragma unroll
    for (int w = 0; w < 8; ++w) { asum += red[w]; bsum += red[8+w]; }
    const float e = asum - bsum, ae = fabsf(e);
    hub = (ae <= 1.f) ? 0.5f*e*e : (ae - 0.5f);
    sm[t]   = (apt > 0.f) ? apt/asum : 0.f;   // aw
    bw_l[t] = (bpt > 0.f) ? bpt/bsum : 0.f;
    __syncthreads();
    aw_r = sm[grow];
    bw_t = bw_l[t];
    const float ax = pc_a[((size_t)b*NP+grow)*3+0];
    const float ay = pc_a[((size_t)b*NP+grow)*3+1];
    const bool  va = aw_r > 0.f;
    #pragma unroll
    for (int cc = 0; cc < 16; ++cc) {
      float r[4];
      #pragma unroll
      for (int e2 = 0; e2 < 4; ++e2) {
        const int col = 32*cc + 4*chunk + e2;
        const float bx = pc_b[((size_t)b*NP+col)*3+0];
        const float by = pc_b[((size_t)b*NP+col)*3+1];
        const bool  vb = bw_l[col] > 0.f;
        const float dx = ax-bx, dy = ay-by;
        const float d  = sqrtf(dx*dx + dy*dy + 1e-12f);
        r[e2] = (va && vb) ? __expf((-INVEPS)*d) : 1.f;   // K=0 for masked pairs
      }
      eKreg[cc] = make_float4(r[0], r[1], r[2], r[3]);
    }
    const float bx0 = pc_b[((size_t)b*NP+t)*3+0];
    const float by0 = pc_b[((size_t)b*NP+t)*3+1];
    const bool  vb0 = bw_t > 0.f;
    #pragma unroll
    for (int i = 0; i < RPB; ++i) {
      const int row = rg*RPB + i;
      const float axi = pc_a[((size_t)b*NP+row)*3+0];  // wave-uniform -> scalar loads
      const float ayi = pc_a[((size_t)b*NP+row)*3+1];
      const bool  vai = sm[row] > 0.f;
      const float dx = axi-bx0, dy = ayi-by0;
      const float d  = sqrtf(dx*dx + dy*dy + 1e-12f);
      eKcol[i] = (vai && vb0) ? __expf((-INVEPS)*d) : 1.f;
    }
    rho_l[t] = 1.f;     // rho(0) = exp(logv=0) = 1
    __syncthreads();
  }

  // ================= main loop =================
  for (int k = 1; k <= ITERS; ++k) {
    const u32 tag = tag_of(k);
    const int par = k & 1;
    const u32* base = pack + ((size_t)par*NB + b)*RG*NP + t;

    // ---- B: u(k) = aw / sum_j ek*rho(k-1)
    {
      const float4* r4p = (const float4*)rho_l;
      float dot = 0.f;
      #pragma unroll
      for (int cc = 0; cc < 16; ++cc) {
        const float4 g4 = r4p[8*cc + chunk];
        const float4 kk = eKreg[cc];
        dot += kk.x*g4.x + kk.y*g4.y + kk.z*g4.z + kk.w*g4.w;
      }
      #pragma unroll
      for (int o = 4; o; o >>= 1) dot += __shfl_xor(dot, o);   // 8-lane row reduce
      if (chunk == 0) u_l[lrow] = aw_r / fmaxf(dot, 1e-38f);
    }
    __syncthreads();   // u_l ready (also: all rho_l reads done)

    // ---- C: publish packed col partial s(k) via atomic exchange (R10)
    float sc_own;
    {
      const float4* u4p = (const float4*)u_l;
      float sc = 0.f;
      #pragma unroll
      for (int i4 = 0; i4 < 16; ++i4) {
        const float4 uu = u4p[i4];
        sc += eKcol[4*i4+0]*uu.x + eKcol[4*i4+1]*uu.y
            + eKcol[4*i4+2]*uu.z + eKcol[4*i4+3]*uu.w;
      }
      sc_own = sc;
      st32_xchg(pack + (((size_t)par*NB + b)*RG + rg)*NP + t, pack_slot(sc, tag));
    }

    // ---- speculative gang issue, POST-publish (R7-proven timing)
    u32 q[RG];
    #pragma unroll
    for (int r = 0; r < RG; ++r)
      if (r != rg) q[r] = ld32(base + (size_t)r*NP);

    // ---- A: check results; sleep-free gang re-poll of laggards (R0-proven:
    // polls carry the data; the IC RT is the natural backoff)
    {
      unsigned pend = 0xFFu & ~(1u << rg);
      long long sweeps = 0;
      while (true) {
        unsigned np = 0;
        #pragma unroll
        for (int r = 0; r < RG; ++r)
          if ((pend >> r) & 1u)
            if ((q[r] & 7u) != tag) np |= (1u << r);
        pend = np;
        if (!pend) break;
        #pragma unroll
        for (int r = 0; r < RG; ++r)        // re-issue ALL pending together
          if ((pend >> r) & 1u)
            q[r] = ld32(base + (size_t)r*NP);
        if (++sweeps > (1LL<<22)) break;    // fail visibly, never hang
      }
      float S = sc_own;
      #pragma unroll
      for (int r = 0; r < RG; ++r)
        if (r != rg) S += __uint_as_float(q[r]);   // <=7 ulp tag noise
      rho_l[t] = bw_t / fmaxf(S, 1e-38f);
    }
    __syncthreads();   // rho_l(k) ready for next B / epilogue
  }

  // ---- epilogue: ot partial = sum d^2 * u_i * ek * rho_j over my row slice
  float acc = 0.f;
  {
    const float ur = u_l[lrow];                  // u(50)
    const float4* r4p = (const float4*)rho_l;    // rho(50)
    #pragma unroll
    for (int cc = 0; cc < 16; ++cc) {
      const float4 g4 = r4p[8*cc + chunk];
      const float4 kk = eKreg[cc];
      const float ek[4] = {kk.x, kk.y, kk.z, kk.w};
      const float vv[4] = {g4.x, g4.y, g4.z, g4.w};
      #pragma unroll
      for (int e2 = 0; e2 < 4; ++e2) {
        const float lk = __logf(fmaxf(ek[e2], 1e-38f));  // d = -EPS*lk; masked: lk=0 -> d2=0
        const float d2 = (EPSV*lk)*(EPSV*lk);
        const float v  = d2 * ur * ek[e2] * vv[e2];
        acc += (ek[e2] > 0.f) ? v : 0.f;
      }
    }
  }
  // block-reduce, publish tagged epi, rg==0 gathers
  sm[t] = acc;
  __syncthreads();
  if (t < 64) {
    float v = 0.f;
    #pragma unroll
    for (int q2 = 0; q2 < 8; ++q2) v += sm[t*8+q2];
    #pragma unroll
    for (int o = 32; o; o >>= 1) v += __shfl_xor(v, o);
    if (t == 0) st64f(epi + (size_t)b*RG + rg, 51.f, v);
  }
  if (rg == 0 && t < RG) {     // gather: 8 lanes, poll + shfl-reduce
    float2 pr;
    long long spins = 0;
    do {
      pr = ld64f(epi + (size_t)b*RG + t);
      if (pr.x == 51.f) break;
      __builtin_amdgcn_s_sleep(1);
    } while (++spins < (1LL<<26));
    float v = pr.y;
    #pragma unroll
    for (int o = 4; o; o >>= 1) v += __shfl_xor(v, o);
    if (t == 0) out[b] = v + hub;
  }
}

extern "C" void kernel_launch(void* const* d_in, const int* in_sizes, int n_in,
                              void* d_out, int out_size, void* d_ws, size_t ws_size,
                              hipStream_t stream) {
  const float* a_mask = (const float*)d_in[0];
  const float* pc_a   = (const float*)d_in[1];
  const float* b_mask = (const float*)d_in[2];
  const float* pc_b   = (const float*)d_in[3];
  float* out = (float*)d_out;
  u32*    pack = (u32*)d_ws;                 // 1 MiB
  float2* epi  = (float2*)(pack + N_PACK);   // + 2 KiB
  (void)in_sizes; (void)n_in; (void)out_size; (void)ws_size;

  emd_kernel<<<NB*RG, NP, 0, stream>>>(a_mask, pc_a, b_mask, pc_b,
                                       pack, epi, out);
}